// Round 4
// baseline (14131.174 us; speedup 1.0000x reference)
//
#include <hip/hip_runtime.h>
#include <stdint.h>

// ---------------------------------------------------------------------------
// Fused spiking-MLP forward: 20 timesteps, B=16384, 784 -> 400 -> 10.
//
// RNG (verified round 2, absmax 0.0): jax threefry PARTITIONABLE semantics:
//   key_t = TF((0,42),(0,t));  element e: bits = x0^x1 of TF(key_t,(0,e));
//   u = bitcast((bits>>9)|0x3f800000)-1;  xi = (x > u).
// fp64 membranes (knife-edge mem>0.5 thresholds).
//
// Round-4 restructure (R3 post-mortem: 2 waves/SIMD latency-bound, 112-reg
// f64 state spilled):
//  * wave = 8 samples x KN neuron-groups (KN=4 for waves sg even: j=lane+64k,
//    k=0..3; KN=3 for sg odd: k=4..6). mem1 = 64/48 VGPRs -> fits 128-VGPR
//    budget -> 4 waves/SIMD (16 waves/CU, 4 blocks/CU).
//  * NO LDS weight staging: W1 read directly from global (L1/L2-hot, ~47
//    B/cyc/CU demand), 4 independent dwordx4 per chunk, TLP hides latency.
//  * 2 barriers/step (xib ready; spk ready) instead of ~100.
//  * xi masks -> SGPRs via readfirstlane (1 word per 2 tiles); accumulate
//    branch is scalar (s_and+s_cbranch), guarding KN f64 adds.
// Block g owns samples g*16..g*16+15 (1024 blocks x 256 threads).
// ---------------------------------------------------------------------------

#define INDIM  784
#define HID    400
#define ODIM   10
#define TSTEPS 20
#define SPB    16         // samples per block
#define XIW    26         // xi words per sample
#define SPW    14         // spike words per sample

__device__ __forceinline__ void tfr(uint32_t& x0, uint32_t& x1, int r) {
  x0 += x1;
  x1 = (x1 << r) | (x1 >> (32 - r));
  x1 ^= x0;
}

__device__ __forceinline__ uint2 tf2x32(uint32_t k0, uint32_t k1,
                                        uint32_t c0, uint32_t c1) {
  uint32_t k2 = k0 ^ k1 ^ 0x1BD11BDAu;
  uint32_t x0 = c0 + k0, x1 = c1 + k1;
  tfr(x0,x1,13); tfr(x0,x1,15); tfr(x0,x1,26); tfr(x0,x1,6);
  x0 += k1; x1 += k2 + 1u;
  tfr(x0,x1,17); tfr(x0,x1,29); tfr(x0,x1,16); tfr(x0,x1,24);
  x0 += k2; x1 += k0 + 2u;
  tfr(x0,x1,13); tfr(x0,x1,15); tfr(x0,x1,26); tfr(x0,x1,6);
  x0 += k0; x1 += k1 + 3u;
  tfr(x0,x1,17); tfr(x0,x1,29); tfr(x0,x1,16); tfr(x0,x1,24);
  x0 += k1; x1 += k2 + 4u;
  tfr(x0,x1,13); tfr(x0,x1,15); tfr(x0,x1,26); tfr(x0,x1,6);
  x0 += k2; x1 += k0 + 5u;
  return make_uint2(x0, x1);
}

__device__ __forceinline__ float bits_to_unif(uint32_t b) {
  return __uint_as_float((b >> 9) | 0x3f800000u) - 1.0f;
}

struct SharedMem {
  uint32_t xib[SPB][XIW];   // 1664 B
  uint32_t spk[SPB][SPW];   // 896 B
};

template<int KN, int KB>
__device__ __forceinline__ void run_wave(
    SharedMem& sh, const int tid, const int g,
    const float* __restrict__ x,  const float* __restrict__ W1,
    const float* __restrict__ b1, const float* __restrict__ W2,
    const float* __restrict__ b2, float* __restrict__ out) {

  const int sg    = tid >> 6;
  const int lane  = tid & 63;
  const int sbase = (sg >> 1) * 8;      // this wave's 8 samples: sbase..+7

  double   mem1[8][KN];                  // 64 (KN=4) / 48 (KN=3) VGPRs
  uint32_t spv[8];
#pragma unroll
  for (int s = 0; s < 8; ++s) {
    spv[s] = 0u;
#pragma unroll
    for (int k = 0; k < KN; ++k) mem1[s][k] = 0.0;
  }

  // per-lane W1 row pointers (j>=400 clamped: harmless dup loads, garbage
  // mem1 never packed into spk)
  const float4* pk[KN];
#pragma unroll
  for (int k = 0; k < KN; ++k) {
    int j = lane + 64 * (KB + k);
    if (j >= HID) j = HID - 1;
    pk[k] = (const float4*)(W1 + (size_t)j * INDIM);
  }

  // layer-2 ownership: tid<160 -> (sample ls, output lo)
  const int ls = tid / ODIM, lo = tid - ls * ODIM;
  const bool l2on = (tid < SPB * ODIM);
  double m2 = 0.0; int s2 = 0, cnt2 = 0;
  const double b2r = l2on ? (double)b2[lo] : 0.0;

  for (int t = 0; t < TSTEPS; ++t) {
    const uint2 kt = tf2x32(0u, 42u, 0u, (uint32_t)t);

    // ---- xi generation: this wave produces samples 4sg..4sg+3 ----
#pragma unroll
    for (int s4 = 0; s4 < 4; ++s4) {
      const int q   = 4 * sg + s4;
      const int row = g * SPB + q;
      for (int c = 0; c < 13; ++c) {
        const int d = c * 64 + lane;
        int xb = 0;
        if (d < INDIM) {
          const uint32_t e = (uint32_t)row * (uint32_t)INDIM + (uint32_t)d;
          uint2 r = tf2x32(kt.x, kt.y, 0u, e);
          xb = x[row * INDIM + d] > bits_to_unif(r.x ^ r.y);
        }
        unsigned long long m = __ballot(xb);
        if (lane == 0) {
          sh.xib[q][2*c]     = (uint32_t)m;
          sh.xib[q][2*c + 1] = (uint32_t)(m >> 32);
        }
      }
    }
    __syncthreads();   // A: xib ready; prev-step spk readers done

    // ---- decay + reset (ref: mem*0.2*(1-spike)) ----
#pragma unroll
    for (int s = 0; s < 8; ++s)
#pragma unroll
      for (int k = 0; k < KN; ++k)
        mem1[s][k] = ((spv[s] >> k) & 1u) ? 0.0 : mem1[s][k] * 0.2;

    // ---- layer 1: 24 tile-pairs (one 32-bit mask word each) + tail ----
    for (int tp = 0; tp < 24; ++tp) {
      uint32_t mm[8];
#pragma unroll
      for (int s = 0; s < 8; ++s)
        mm[s] = __builtin_amdgcn_readfirstlane(sh.xib[sbase + s][tp]);
      const float4* pt[KN];
#pragma unroll
      for (int k = 0; k < KN; ++k) pt[k] = pk[k] + tp * 8;
#pragma unroll
      for (int cc = 0; cc < 8; ++cc) {
        union { float4 v; float f[4]; } w4[KN];
#pragma unroll
        for (int k = 0; k < KN; ++k) w4[k].v = pt[k][cc];
#pragma unroll
        for (int dt = 0; dt < 4; ++dt) {
          const int bit = ((cc >> 2) << 4) + ((cc & 3) << 2) + dt;
          double wd[KN];
#pragma unroll
          for (int k = 0; k < KN; ++k) wd[k] = (double)w4[k].f[dt];
#pragma unroll
          for (int s = 0; s < 8; ++s) {
            if (mm[s] & (1u << bit)) {   // mm uniform -> scalar branch
#pragma unroll
              for (int k = 0; k < KN; ++k) mem1[s][k] += wd[k];
            }
          }
        }
      }
    }
    {   // tail tile 48: d = 768..783, mask word 24 bits 0..15
      uint32_t mm[8];
#pragma unroll
      for (int s = 0; s < 8; ++s)
        mm[s] = __builtin_amdgcn_readfirstlane(sh.xib[sbase + s][24]);
      const float4* pt[KN];
#pragma unroll
      for (int k = 0; k < KN; ++k) pt[k] = pk[k] + 192;
#pragma unroll
      for (int cc = 0; cc < 4; ++cc) {
        union { float4 v; float f[4]; } w4[KN];
#pragma unroll
        for (int k = 0; k < KN; ++k) w4[k].v = pt[k][cc];
#pragma unroll
        for (int dt = 0; dt < 4; ++dt) {
          const int bit = (cc << 2) + dt;
          double wd[KN];
#pragma unroll
          for (int k = 0; k < KN; ++k) wd[k] = (double)w4[k].f[dt];
#pragma unroll
          for (int s = 0; s < 8; ++s) {
            if (mm[s] & (1u << bit)) {
#pragma unroll
              for (int k = 0; k < KN; ++k) mem1[s][k] += wd[k];
            }
          }
        }
      }
    }

    // ---- finalize layer 1: + b1, threshold, pack spikes ----
    double bb[KN];
#pragma unroll
    for (int k = 0; k < KN; ++k) {
      const int j = lane + 64 * (KB + k);
      bb[k] = (j < HID) ? (double)b1[j] : 0.0;
    }
#pragma unroll
    for (int s = 0; s < 8; ++s) {
      uint32_t msk = 0u;
#pragma unroll
      for (int k = 0; k < KN; ++k) {
        mem1[s][k] += bb[k];
        if (mem1[s][k] > 0.5) msk |= (1u << k);
      }
      spv[s] = msk;
#pragma unroll
      for (int k = 0; k < KN; ++k) {
        unsigned long long bm = __ballot((msk >> k) & 1u);
        if (lane == 0) {
          sh.spk[sbase + s][2*(KB + k)]     = (uint32_t)bm;
          sh.spk[sbase + s][2*(KB + k) + 1] = (uint32_t)(bm >> 32);
        }
      }
    }
    __syncthreads();   // B: spk ready

    // ---- layer 2: 160 pairs, bit-sparse fp64 dot over W2 rows ----
    if (l2on) {
      double a2  = s2 ? 0.0 : m2 * 0.2;
      double dot = 0.0;
      const float* w2r = W2 + lo * HID;
      for (int w = 0; w < 13; ++w) {
        uint32_t bits = sh.spk[ls][w];
        if (w == 12) bits &= 0xFFFFu;      // j in [384,400)
        const int jb = 32 * w;
        while (bits) {
          const int bi = __ffs(bits) - 1;
          bits &= bits - 1u;
          dot += (double)w2r[jb + bi];
        }
      }
      m2 = (a2 + dot) + b2r;
      s2 = (m2 > 0.5) ? 1 : 0;
      cnt2 += s2;
    }
  }

  if (l2on)
    out[(g * SPB + ls) * ODIM + lo] = (float)((double)cnt2 / 20.0);
}

__global__ __launch_bounds__(256, 4)
void snn_fused(const float* __restrict__ x,  const float* __restrict__ W1,
               const float* __restrict__ b1, const float* __restrict__ W2,
               const float* __restrict__ b2, float* __restrict__ out) {
  __shared__ SharedMem sh;
  const int tid = threadIdx.x;
  const int g   = blockIdx.x;
  if (((tid >> 6) & 1) == 0)
    run_wave<4, 0>(sh, tid, g, x, W1, b1, W2, b2, out);
  else
    run_wave<3, 4>(sh, tid, g, x, W1, b1, W2, b2, out);
}

extern "C" void kernel_launch(void* const* d_in, const int* in_sizes, int n_in,
                              void* d_out, int out_size, void* d_ws, size_t ws_size,
                              hipStream_t stream) {
  const float* x  = (const float*)d_in[0];
  const float* W1 = (const float*)d_in[1];
  const float* b1 = (const float*)d_in[2];
  const float* W2 = (const float*)d_in[3];
  const float* b2 = (const float*)d_in[4];
  // d_in[5] = time_window (int, ==20) — compile-time constant here.
  float* out = (float*)d_out;
  hipLaunchKernelGGL(snn_fused, dim3(1024), dim3(256), 0, stream,
                     x, W1, b1, W2, b2, out);
}

// Round 5
// 10582.322 us; speedup vs baseline: 1.3354x; 1.3354x over previous
//
#include <hip/hip_runtime.h>
#include <stdint.h>

// ---------------------------------------------------------------------------
// Fused spiking-MLP forward: 20 timesteps, B=16384, 784 -> 400 -> 10.
//
// RNG (verified round 2, absmax 0.0): jax threefry PARTITIONABLE semantics:
//   key_t = TF((0,42),(0,t));  element e: bits = x0^x1 of TF(key_t,(0,e));
//   u = bitcast((bits>>9)|0x3f800000)-1;  xi = (x > u).
// fp64 membranes (knife-edge mem>0.5 thresholds; any fp64 order is safe,
// fp32 is not).
//
// Round-5 structure (post-mortems R3: occupancy>=12 waves/CU needed;
// R4: per-lane global W1 rows uncoalesced -> 4.8GB fetch, and 128-VGPR cap
// spilled mem1 -> 10GB scratch writes):
//  * R2 skeleton: LDS weight tile wt[16][448] f32 (stage coalesced from
//    global, 2 barriers/tile), conflict-free [dt][j] b32 reads.
//  * Wave = 8 samples x half neurons (waves 0,2: k=0..3 / waves 1,3: k=4..6)
//    -> cvt + LDS reads per fp64-add HALVED vs R2; adjacent k offsets are
//    64 dwords apart -> ds_read2_b32 fusable.
//  * mem1[8][KN<=4] = 64 f64 VGPRs; __launch_bounds__(256,3) (~170 cap) so
//    nothing spills; 12 waves/CU = R2's measured occupancy.
// Block g owns samples g*16..g*16+15 (1024 blocks x 256 threads).
// ---------------------------------------------------------------------------

#define INDIM  784
#define HID    400
#define ODIM   10
#define TSTEPS 20
#define SPB    16         // samples per block
#define TD     16         // d-tile size
#define NT     49         // 784/16
#define WTJ    448        // padded neuron rows
#define XIW    26         // xi words per sample (25 used, +1 pad)
#define SPW    14         // spike words per sample

__device__ __forceinline__ void tfr(uint32_t& x0, uint32_t& x1, int r) {
  x0 += x1;
  x1 = (x1 << r) | (x1 >> (32 - r));
  x1 ^= x0;
}

__device__ __forceinline__ uint2 tf2x32(uint32_t k0, uint32_t k1,
                                        uint32_t c0, uint32_t c1) {
  uint32_t k2 = k0 ^ k1 ^ 0x1BD11BDAu;
  uint32_t x0 = c0 + k0, x1 = c1 + k1;
  tfr(x0,x1,13); tfr(x0,x1,15); tfr(x0,x1,26); tfr(x0,x1,6);
  x0 += k1; x1 += k2 + 1u;
  tfr(x0,x1,17); tfr(x0,x1,29); tfr(x0,x1,16); tfr(x0,x1,24);
  x0 += k2; x1 += k0 + 2u;
  tfr(x0,x1,13); tfr(x0,x1,15); tfr(x0,x1,26); tfr(x0,x1,6);
  x0 += k0; x1 += k1 + 3u;
  tfr(x0,x1,17); tfr(x0,x1,29); tfr(x0,x1,16); tfr(x0,x1,24);
  x0 += k1; x1 += k2 + 4u;
  tfr(x0,x1,13); tfr(x0,x1,15); tfr(x0,x1,26); tfr(x0,x1,6);
  x0 += k2; x1 += k0 + 5u;
  return make_uint2(x0, x1);
}

__device__ __forceinline__ float bits_to_unif(uint32_t b) {
  return __uint_as_float((b >> 9) | 0x3f800000u) - 1.0f;
}

struct SharedMem {
  float    wt[TD][WTJ];     // 28672 B
  uint32_t xib[SPB][XIW];   // 1664 B
  uint32_t spk[SPB][SPW];   // 896 B
};

template<int KN, int KB>
__device__ __forceinline__ void run_wave(
    SharedMem& sh, const int tid, const int g,
    const float* __restrict__ x,  const float* __restrict__ W1,
    const float* __restrict__ b1, const float* __restrict__ W2,
    const float* __restrict__ b2, float* __restrict__ out) {

  const int sg    = tid >> 6;
  const int lane  = tid & 63;
  const int sbase = (sg >> 1) * 8;      // this wave's 8 samples: sbase..+7

  double   mem1[8][KN];                 // 64 (KN=4) / 48 (KN=3) VGPRs
  uint32_t spv[8];
#pragma unroll
  for (int s = 0; s < 8; ++s) {
    spv[s] = 0u;
#pragma unroll
    for (int k = 0; k < KN; ++k) mem1[s][k] = 0.0;
  }

  // b1 cached in f64 registers; zero for pad neurons (j>=400 never fire)
  double b1r[KN];
#pragma unroll
  for (int k = 0; k < KN; ++k) {
    const int j = lane + 64 * (KB + k);
    b1r[k] = (j < HID) ? (double)b1[j] : 0.0;
  }

  // layer-2 ownership: tid<160 -> (sample ls, output lo)
  const int ls = tid / ODIM, lo = tid - ls * ODIM;
  const bool l2on = (tid < SPB * ODIM);
  double m2 = 0.0; int s2 = 0, cnt2 = 0;
  const double b2r = l2on ? (double)b2[lo] : 0.0;

  for (int t = 0; t < TSTEPS; ++t) {
    const uint2 kt = tf2x32(0u, 42u, 0u, (uint32_t)t);

    // ---- xi generation: wave sg produces samples 4sg..4sg+3 ----
#pragma unroll
    for (int s4 = 0; s4 < 4; ++s4) {
      const int q   = 4 * sg + s4;
      const int row = g * SPB + q;
      for (int c = 0; c < 13; ++c) {
        const int d = c * 64 + lane;
        int xb = 0;
        if (d < INDIM) {
          const uint32_t e = (uint32_t)row * (uint32_t)INDIM + (uint32_t)d;
          uint2 r = tf2x32(kt.x, kt.y, 0u, e);
          xb = x[row * INDIM + d] > bits_to_unif(r.x ^ r.y);
        }
        unsigned long long m = __ballot(xb);
        if (lane == 0) {
          sh.xib[q][2*c]     = (uint32_t)m;
          sh.xib[q][2*c + 1] = (uint32_t)(m >> 32);
        }
      }
    }

    // ---- decay + reset (ref: mem*0.2*(1-spike)) ----
#pragma unroll
    for (int s = 0; s < 8; ++s)
#pragma unroll
      for (int k = 0; k < KN; ++k)
        mem1[s][k] = ((spv[s] >> k) & 1u) ? 0.0 : mem1[s][k] * 0.2;

    // ---- layer 1: 49 LDS-staged d-tiles ----
    for (int td = 0; td < NT; ++td) {
      const int d0 = td * TD;
      __syncthreads();   // prev tile consumed by ALL waves; xib ready (td=0)

      // stage W1[0:448][d0:d0+16] -> wt[dt][jj] (coalesced 64B/row reads)
#pragma unroll
      for (int half = 0; half < 2; ++half) {
        const int jj = tid + 256 * half;
        if (jj < WTJ) {
          float v[TD];
          if (jj < HID) {
            const float4* src = (const float4*)(W1 + (size_t)jj * INDIM + d0);
            float4 a = src[0], b = src[1], c = src[2], dd = src[3];
            v[0]=a.x; v[1]=a.y; v[2]=a.z; v[3]=a.w;
            v[4]=b.x; v[5]=b.y; v[6]=b.z; v[7]=b.w;
            v[8]=c.x; v[9]=c.y; v[10]=c.z; v[11]=c.w;
            v[12]=dd.x; v[13]=dd.y; v[14]=dd.z; v[15]=dd.w;
          } else {
#pragma unroll
            for (int q = 0; q < TD; ++q) v[q] = 0.0f;
          }
#pragma unroll
          for (int dt = 0; dt < TD; ++dt) sh.wt[dt][jj] = v[dt];
        }
      }
      __syncthreads();

      // masks for this tile (wave-uniform per sample) -> SGPRs
      const int sh16 = (td & 1) * 16;
      uint32_t mm[8];
#pragma unroll
      for (int s = 0; s < 8; ++s)
        mm[s] = (__builtin_amdgcn_readfirstlane(sh.xib[sbase + s][td >> 1])
                 >> sh16) & 0xFFFFu;

#pragma unroll 4
      for (int dt = 0; dt < TD; ++dt) {
        double wd[KN];
#pragma unroll
        for (int k = 0; k < KN; ++k)
          wd[k] = (double)sh.wt[dt][lane + 64 * (KB + k)];
#pragma unroll
        for (int s = 0; s < 8; ++s) {
          if (mm[s] & (1u << dt)) {      // uniform -> scalar branch
#pragma unroll
            for (int k = 0; k < KN; ++k) mem1[s][k] += wd[k];
          }
        }
      }
    }

    // ---- finalize layer 1: + b1, threshold, pack spikes ----
#pragma unroll
    for (int s = 0; s < 8; ++s) {
      uint32_t msk = 0u;
#pragma unroll
      for (int k = 0; k < KN; ++k) {
        mem1[s][k] += b1r[k];
        if (mem1[s][k] > 0.5) msk |= (1u << k);   // pad neurons never fire
      }
      spv[s] = msk;
#pragma unroll
      for (int k = 0; k < KN; ++k) {
        unsigned long long bm = __ballot((msk >> k) & 1u);
        if (lane == 0) {
          sh.spk[sbase + s][2*(KB + k)]     = (uint32_t)bm;
          sh.spk[sbase + s][2*(KB + k) + 1] = (uint32_t)(bm >> 32);
        }
      }
    }
    __syncthreads();   // spk ready (also orders next-step xib writes)

    // ---- layer 2: 160 pairs, bit-sparse fp64 dot over W2 rows ----
    if (l2on) {
      double a2  = s2 ? 0.0 : m2 * 0.2;
      double dot = 0.0;
      const float* w2r = W2 + lo * HID;
      for (int w = 0; w < 13; ++w) {
        uint32_t bits = sh.spk[ls][w];
        if (w == 12) bits &= 0xFFFFu;     // j in [384,400)
        const int jb = 32 * w;
        while (bits) {
          const int bi = __ffs(bits) - 1;
          bits &= bits - 1u;
          dot += (double)w2r[jb + bi];
        }
      }
      m2 = (a2 + dot) + b2r;
      s2 = (m2 > 0.5) ? 1 : 0;
      cnt2 += s2;
    }
  }

  if (l2on)
    out[(g * SPB + ls) * ODIM + lo] = (float)((double)cnt2 / 20.0);
}

__global__ __launch_bounds__(256, 3)
void snn_fused(const float* __restrict__ x,  const float* __restrict__ W1,
               const float* __restrict__ b1, const float* __restrict__ W2,
               const float* __restrict__ b2, float* __restrict__ out) {
  __shared__ SharedMem sh;
  const int tid = threadIdx.x;
  const int g   = blockIdx.x;
  if (((tid >> 6) & 1) == 0)
    run_wave<4, 0>(sh, tid, g, x, W1, b1, W2, b2, out);
  else
    run_wave<3, 4>(sh, tid, g, x, W1, b1, W2, b2, out);
}

extern "C" void kernel_launch(void* const* d_in, const int* in_sizes, int n_in,
                              void* d_out, int out_size, void* d_ws, size_t ws_size,
                              hipStream_t stream) {
  const float* x  = (const float*)d_in[0];
  const float* W1 = (const float*)d_in[1];
  const float* b1 = (const float*)d_in[2];
  const float* W2 = (const float*)d_in[3];
  const float* b2 = (const float*)d_in[4];
  // d_in[5] = time_window (int, ==20) — compile-time constant here.
  float* out = (float*)d_out;
  hipLaunchKernelGGL(snn_fused, dim3(1024), dim3(256), 0, stream,
                     x, W1, b1, W2, b2, out);
}

// Round 6
// 8399.133 us; speedup vs baseline: 1.6825x; 1.2599x over previous
//
#include <hip/hip_runtime.h>
#include <stdint.h>

// ---------------------------------------------------------------------------
// Fused spiking-MLP forward: 20 timesteps, B=16384, 784 -> 400 -> 10.
//
// RNG (verified round 2, absmax 0.0): jax threefry PARTITIONABLE semantics:
//   key_t = TF((0,42),(0,t));  element e: bits = x0^x1 of TF(key_t,(0,e));
//   u = bitcast((bits>>9)|0x3f800000)-1;  xi = (x > u).
// fp64 membranes (knife-edge mem>0.5 thresholds; f64 matches np-f64 ref).
//
// Round-6 = R2 skeleton (6.18 ms, the only structure that benched well:
// 4 samples/wave, all 7 neuron-groups/thread, uniform code path, 16 waves/CU)
// with ONE change, targeting R2's measured bottleneck (LDS pipe ~5.3/6.2 ms):
//  * weight tile TRANSPOSED to wt[j][20] (pad 16->20 dwords = 80 B rows):
//      - reads: 28x ds_read_b128 per wave/tile (was 112x ds_read_b32),
//        44 -> ~85 B/cyc effective LDS BW;
//      - writes: 4x ds_write_b128 per row (was 16 scattered b32);
//      - pad-20 rows are 16-B aligned and start-bank pattern (20*lane mod 32)
//        covers all 32 banks per 8-lane pass -> conflict-free b128 R/W.
//  * fp64 add order per (sample,neuron) unchanged -> absmax stays 0.0.
// R3/R4/R5 post-mortems: 8-sample waves, k-splitting, per-lane global rows,
// and dual-template wave paths ALL regressed; do not revisit.
// ---------------------------------------------------------------------------

#define INDIM  784
#define HID    400
#define ODIM   10
#define TSTEPS 20
#define SPB    16         // samples per block
#define TD     16         // d-tile size
#define NT     49         // 784/16
#define WTJ    448        // padded neuron rows
#define WPAD   20         // dwords per tile row (16 data + 4 pad, 16B-aligned)
#define XIW    26         // xi words per sample (25 used, +1 pad)
#define SPW    14         // spike words per sample

__device__ __forceinline__ void tfr(uint32_t& x0, uint32_t& x1, int r) {
  x0 += x1;
  x1 = (x1 << r) | (x1 >> (32 - r));
  x1 ^= x0;
}

__device__ __forceinline__ uint2 tf2x32(uint32_t k0, uint32_t k1,
                                        uint32_t c0, uint32_t c1) {
  uint32_t k2 = k0 ^ k1 ^ 0x1BD11BDAu;
  uint32_t x0 = c0 + k0, x1 = c1 + k1;
  tfr(x0,x1,13); tfr(x0,x1,15); tfr(x0,x1,26); tfr(x0,x1,6);
  x0 += k1; x1 += k2 + 1u;
  tfr(x0,x1,17); tfr(x0,x1,29); tfr(x0,x1,16); tfr(x0,x1,24);
  x0 += k2; x1 += k0 + 2u;
  tfr(x0,x1,13); tfr(x0,x1,15); tfr(x0,x1,26); tfr(x0,x1,6);
  x0 += k0; x1 += k1 + 3u;
  tfr(x0,x1,17); tfr(x0,x1,29); tfr(x0,x1,16); tfr(x0,x1,24);
  x0 += k1; x1 += k2 + 4u;
  tfr(x0,x1,13); tfr(x0,x1,15); tfr(x0,x1,26); tfr(x0,x1,6);
  x0 += k2; x1 += k0 + 5u;
  return make_uint2(x0, x1);
}

__device__ __forceinline__ float bits_to_unif(uint32_t b) {
  return __uint_as_float((b >> 9) | 0x3f800000u) - 1.0f;
}

struct SharedMem {
  float    wt[WTJ][WPAD];   // 35840 B  (tile, layout [j][dt], pad 4)
  uint32_t xib[SPB][XIW];   // 1664 B
  uint32_t spk[SPB][SPW];   // 896 B
};                          // total 38400 B -> 4 blocks/CU

__global__ __launch_bounds__(256, 4)
void snn_fused(const float* __restrict__ x,  const float* __restrict__ W1,
               const float* __restrict__ b1, const float* __restrict__ W2,
               const float* __restrict__ b2, float* __restrict__ out) {
  __shared__ SharedMem sh;

  const int tid  = threadIdx.x;
  const int g    = blockIdx.x;           // 0..1023
  const int sg   = tid >> 6;             // wave id = sample group
  const int lane = tid & 63;             // neuron-thread index

  // persistent per-thread layer-1 state: mem1[s][k] for samples 4sg+s,
  // neurons j = lane + 64k (j>=400 are zero-padded dummies)
  double   mem1[4][7];
  uint32_t spv[4];
#pragma unroll
  for (int s = 0; s < 4; ++s) {
    spv[s] = 0u;
#pragma unroll
    for (int k = 0; k < 7; ++k) mem1[s][k] = 0.0;
  }

  // layer-2 ownership: tid<160 -> (sample ls, output lo)
  const int ls = tid / ODIM, lo = tid - ls * ODIM;
  const bool l2on = (tid < SPB * ODIM);
  double m2 = 0.0; int s2 = 0, cnt2 = 0;
  const double b2r = l2on ? (double)b2[lo] : 0.0;

  for (int t = 0; t < TSTEPS; ++t) {
    const uint2 kt = tf2x32(0u, 42u, 0u, (uint32_t)t);

    // ---- xi generation: wave sg produces samples 4sg..4sg+3 ----
#pragma unroll
    for (int s4 = 0; s4 < 4; ++s4) {
      const int q   = 4 * sg + s4;
      const int row = g * SPB + q;
      for (int c = 0; c < 13; ++c) {
        const int d = c * 64 + lane;
        int xb = 0;
        if (d < INDIM) {
          const uint32_t e = (uint32_t)row * (uint32_t)INDIM + (uint32_t)d;
          uint2 r = tf2x32(kt.x, kt.y, 0u, e);
          xb = x[row * INDIM + d] > bits_to_unif(r.x ^ r.y);
        }
        unsigned long long m = __ballot(xb);
        if (lane == 0) {
          sh.xib[q][2*c]     = (uint32_t)m;
          sh.xib[q][2*c + 1] = (uint32_t)(m >> 32);
        }
      }
    }

    // ---- decay + reset (ref: mem*0.2*(1-spike)) ----
#pragma unroll
    for (int s = 0; s < 4; ++s)
#pragma unroll
      for (int k = 0; k < 7; ++k)
        mem1[s][k] = ((spv[s] >> k) & 1u) ? 0.0 : mem1[s][k] * 0.2;

    // ---- layer 1: 49 LDS-staged d-tiles ----
    for (int td = 0; td < NT; ++td) {
      const int d0 = td * TD;
      __syncthreads();   // prev tile consumed by all waves; xib ready (td=0)

      // stage W1[jj][d0:d0+16] -> wt[jj][0:16]; 4x ds_write_b128 per row,
      // global reads coalesced 64 B/row
#pragma unroll
      for (int half = 0; half < 2; ++half) {
        const int jj = tid + 256 * half;
        if (jj < WTJ) {
          float4 v0, v1, v2, v3;
          if (jj < HID) {
            const float4* src = (const float4*)(W1 + (size_t)jj * INDIM + d0);
            v0 = src[0]; v1 = src[1]; v2 = src[2]; v3 = src[3];
          } else {
            v0 = v1 = v2 = v3 = make_float4(0.f, 0.f, 0.f, 0.f);
          }
          float4* dst = (float4*)&sh.wt[jj][0];   // 80B rows: 16B-aligned
          dst[0] = v0; dst[1] = v1; dst[2] = v2; dst[3] = v3;
        }
      }
      __syncthreads();

      // masks for this tile (wave-uniform per sample) -> SGPRs
      const int sh16 = (td & 1) * 16;
      uint32_t xw[4];
#pragma unroll
      for (int s = 0; s < 4; ++s)
        xw[s] = (__builtin_amdgcn_readfirstlane(sh.xib[4*sg + s][td >> 1])
                 >> sh16) & 0xFFFFu;

#pragma unroll
      for (int dtq = 0; dtq < 4; ++dtq) {
        // 7x ds_read_b128: 4 consecutive dt for each neuron-group k
        float4 w4[7];
#pragma unroll
        for (int k = 0; k < 7; ++k)
          w4[k] = *(const float4*)&sh.wt[lane + 64 * k][4 * dtq];
#pragma unroll
        for (int dt4 = 0; dt4 < 4; ++dt4) {
          const int bit = 4 * dtq + dt4;
          double wd[7];
          const float* wf = (const float*)&w4[0];   // w4[k] component dt4
#pragma unroll
          for (int k = 0; k < 7; ++k) wd[k] = (double)wf[4 * k + dt4];
#pragma unroll
          for (int s = 0; s < 4; ++s) {
            if (xw[s] & (1u << bit)) {   // uniform -> scalar branch
#pragma unroll
              for (int k = 0; k < 7; ++k) mem1[s][k] += wd[k];
            }
          }
        }
      }
    }

    // ---- finalize layer 1: + b1, threshold, pack spikes ----
#pragma unroll
    for (int s = 0; s < 4; ++s) {
      uint32_t msk = 0u;
#pragma unroll
      for (int k = 0; k < 7; ++k) {
        const int j = lane + 64 * k;
        const double bb = (j < HID) ? (double)b1[j] : 0.0;
        mem1[s][k] += bb;
        if (mem1[s][k] > 0.5) msk |= (1u << k);   // pad neurons never fire
      }
      spv[s] = msk;
#pragma unroll
      for (int k = 0; k < 7; ++k) {
        unsigned long long bm = __ballot((msk >> k) & 1u);
        if (lane == 0) {
          sh.spk[4*sg + s][2*k]     = (uint32_t)bm;
          sh.spk[4*sg + s][2*k + 1] = (uint32_t)(bm >> 32);
        }
      }
    }
    __syncthreads();   // spk ready (also orders next-step xib writes)

    // ---- layer 2: 160 pairs, bit-sparse fp64 dot over W2 rows ----
    if (l2on) {
      double a2  = s2 ? 0.0 : m2 * 0.2;
      double dot = 0.0;
      const float* w2r = W2 + lo * HID;
      for (int w = 0; w < 13; ++w) {
        uint32_t bits = sh.spk[ls][w];
        if (w == 12) bits &= 0xFFFFu;     // j in [384,400)
        const int jb = 32 * w;
        while (bits) {
          const int bi = __ffs(bits) - 1;
          bits &= bits - 1u;
          dot += (double)w2r[jb + bi];
        }
      }
      m2 = (a2 + dot) + b2r;
      s2 = (m2 > 0.5) ? 1 : 0;
      cnt2 += s2;
    }
  }

  if (l2on)
    out[(g * SPB + ls) * ODIM + lo] = (float)((double)cnt2 / 20.0);
}

extern "C" void kernel_launch(void* const* d_in, const int* in_sizes, int n_in,
                              void* d_out, int out_size, void* d_ws, size_t ws_size,
                              hipStream_t stream) {
  const float* x  = (const float*)d_in[0];
  const float* W1 = (const float*)d_in[1];
  const float* b1 = (const float*)d_in[2];
  const float* W2 = (const float*)d_in[3];
  const float* b2 = (const float*)d_in[4];
  // d_in[5] = time_window (int, ==20) — compile-time constant here.
  float* out = (float*)d_out;
  hipLaunchKernelGGL(snn_fused, dim3(1024), dim3(256), 0, stream,
                     x, W1, b1, W2, b2, out);
}